// Round 9
// baseline (129.364 us; speedup 1.0000x reference)
//
#include <hip/hip_runtime.h>
#include <hip/hip_bf16.h>
#include <hip/hip_cooperative_groups.h>

namespace cg = cooperative_groups;

// AggregationLoss. preds [32,6,256,256] f32, targets [32,2,256,256] i32.
// sim = preds[:,2:6]; text = targets[:,0]; kernel = targets[:,1]; MAX_T=16.
// Per sample: G[t] = mean of sim over kernel==t; per-pixel
// loss = log1p(max(||sim_p - G[text_p]|| - 0.5, 0)^2); per-instance mean over
// text==t for valid t (t>=1, k_cnt>0, t_cnt>0); output = mean over valid.
//
// R9: single cooperative kernel, LAUNCH-SAFE version of R8.
//  - R8 post-mortem: coop launch silently failed (out stayed zero). Suspects:
//    2-D grid + 39 KB LDS at 2 blocks/CU. Fix: 1-D grid, LDS ~2 KB (no pixel
//    stash - phase 2 re-reads from L3, R4 lesson says that's nearly free),
//    and CHECK the launch return code with a fallback to the proven R7
//    3-kernel path (43.8 us) so the kernel can never silently not-run.
//  - Keep: register accumulators, DPP wave-reduce, packed int counts,
//    no launch_bounds min-waves (R6 spill lesson).

#define P_PIX 65536
#define NS 32
#define NB 16              // blocks per sample; fused grid = 512 (2 blocks/CU)
#define SP_F 96            // stats partial: kcnt[0..14] ksum[15..74] tcnt[75..89]
#define WS_STATS_OFF 0
#define WS_ISUM_OFF (NS * NB * SP_F)   // isum partials: [NS][NB][16]

// ---- DPP wave(64) sum: result lands in lane 63 (R7 proven) ----
template <int CTRL, int RM>
__device__ __forceinline__ float dpp_mov_f(float v) {
    return __int_as_float(
        __builtin_amdgcn_update_dpp(0, __float_as_int(v), CTRL, RM, 0xf, true));
}
template <int CTRL, int RM>
__device__ __forceinline__ int dpp_mov_i(int v) {
    return __builtin_amdgcn_update_dpp(0, v, CTRL, RM, 0xf, true);
}
__device__ __forceinline__ float wave_sum_f(float v) {
    v += dpp_mov_f<0x111, 0xf>(v);
    v += dpp_mov_f<0x112, 0xf>(v);
    v += dpp_mov_f<0x114, 0xf>(v);
    v += dpp_mov_f<0x118, 0xf>(v);
    v += dpp_mov_f<0x142, 0xa>(v);
    v += dpp_mov_f<0x143, 0xc>(v);
    return v;
}
__device__ __forceinline__ int wave_sum_i(int v) {
    v += dpp_mov_i<0x111, 0xf>(v);
    v += dpp_mov_i<0x112, 0xf>(v);
    v += dpp_mov_i<0x114, 0xf>(v);
    v += dpp_mov_i<0x118, 0xf>(v);
    v += dpp_mov_i<0x142, 0xa>(v);
    v += dpp_mov_i<0x143, 0xc>(v);
    return v;
}

// ---------------- phase bodies (shared by fused + fallback) ----------------

__device__ __forceinline__ void phase_stats(const float* __restrict__ preds,
                                            const int* __restrict__ targets,
                                            float* __restrict__ ws,
                                            int s, int b, int tid) {
    const int lane = tid & 63;
    const int w = tid >> 6;

    float ksum[60];
    #pragma unroll
    for (int k = 0; k < 60; ++k) ksum[k] = 0.0f;
    int cnt[15];               // kcnt low16 | tcnt high16 (block-local <= 4096)
    #pragma unroll
    for (int k = 0; k < 15; ++k) cnt[k] = 0;

    const float* sim  = preds + (size_t)s * 6 * P_PIX + 2 * (size_t)P_PIX;
    const int*   text = targets + (size_t)s * 2 * P_PIX;
    const int*   kern = text + P_PIX;

    #pragma unroll
    for (int it = 0; it < 4; ++it) {
        const int p4 = b * 1024 + it * 256 + tid;   // float4 index
        const int4   tb4 = ((const int4*)text)[p4];
        const int4   kb4 = ((const int4*)kern)[p4];
        const float4 v0 = ((const float4*)(sim))[p4];
        const float4 v1 = ((const float4*)(sim + P_PIX))[p4];
        const float4 v2 = ((const float4*)(sim + 2 * P_PIX))[p4];
        const float4 v3 = ((const float4*)(sim + 3 * P_PIX))[p4];
        const int tbv[4] = {tb4.x, tb4.y, tb4.z, tb4.w};
        const int kbv[4] = {kb4.x, kb4.y, kb4.z, kb4.w};
        const float a[4][4] = {{v0.x, v1.x, v2.x, v3.x}, {v0.y, v1.y, v2.y, v3.y},
                               {v0.z, v1.z, v2.z, v3.z}, {v0.w, v1.w, v2.w, v3.w}};
        #pragma unroll
        for (int j = 0; j < 4; ++j) {
            const int kb = kbv[j], tb = tbv[j];
            #pragma unroll
            for (int t = 1; t < 16; ++t) {
                const bool pk = (kb == t);
                cnt[t - 1] += (pk ? 1 : 0) + ((tb == t) ? 0x10000 : 0);
                const float m = pk ? 1.0f : 0.0f;
                #pragma unroll
                for (int c = 0; c < 4; ++c)
                    ksum[(t - 1) * 4 + c] = fmaf(m, a[j][c], ksum[(t - 1) * 4 + c]);
            }
        }
    }

    #pragma unroll
    for (int k = 0; k < 60; ++k) ksum[k] = wave_sum_f(ksum[k]);
    #pragma unroll
    for (int k = 0; k < 15; ++k) cnt[k] = wave_sum_i(cnt[k]);

    __shared__ float wsum[4][60];
    __shared__ int   wcnt[4][15];
    if (lane == 63) {
        #pragma unroll
        for (int k = 0; k < 60; ++k) wsum[w][k] = ksum[k];
        #pragma unroll
        for (int k = 0; k < 15; ++k) wcnt[w][k] = cnt[k];
    }
    __syncthreads();

    float* part = ws + WS_STATS_OFF + (size_t)(s * NB + b) * SP_F;
    if (tid < 60) {
        part[15 + tid] = (wsum[0][tid] + wsum[1][tid]) + (wsum[2][tid] + wsum[3][tid]);
    } else if (tid >= 64 && tid < 79) {
        const int k = tid - 64;
        const int ctot = (wcnt[0][k] + wcnt[1][k]) + (wcnt[2][k] + wcnt[3][k]);
        part[k] = (float)(ctot & 0xffff);
        part[75 + k] = (float)(((unsigned)ctot) >> 16);
    }
    __syncthreads();
}

__device__ __forceinline__ void compute_G(const float* __restrict__ ws,
                                          int s, int tid, float (*G4)[4]) {
    __shared__ float tmp[90];
    if (tid < 90) {
        const float* base = ws + WS_STATS_OFF + (size_t)s * NB * SP_F + tid;
        float v = 0.0f;
        #pragma unroll
        for (int pb = 0; pb < NB; ++pb) v += base[pb * SP_F];
        tmp[tid] = v;
    }
    __syncthreads();
    if (tid < 60) G4[1 + (tid >> 2)][tid & 3] = tmp[15 + tid] / fmaxf(tmp[tid >> 2], 1.0f);
    if (tid >= 64 && tid < 68) G4[0][tid - 64] = 0.0f;
    __syncthreads();
}

__device__ __forceinline__ void phase_loss(const float* __restrict__ preds,
                                           const int* __restrict__ targets,
                                           float* __restrict__ ws,
                                           int s, int b, int tid,
                                           const float (*G4)[4]) {
    const int lane = tid & 63;
    const int w = tid >> 6;

    float isum[15];
    #pragma unroll
    for (int k = 0; k < 15; ++k) isum[k] = 0.0f;

    const float* sim  = preds + (size_t)s * 6 * P_PIX + 2 * (size_t)P_PIX;
    const int*   text = targets + (size_t)s * 2 * P_PIX;

    #pragma unroll
    for (int it = 0; it < 4; ++it) {
        const int p4 = b * 1024 + it * 256 + tid;
        const int4   tb4 = ((const int4*)text)[p4];
        const float4 v0 = ((const float4*)(sim))[p4];
        const float4 v1 = ((const float4*)(sim + P_PIX))[p4];
        const float4 v2 = ((const float4*)(sim + 2 * P_PIX))[p4];
        const float4 v3 = ((const float4*)(sim + 3 * P_PIX))[p4];
        const int tbv[4] = {tb4.x, tb4.y, tb4.z, tb4.w};
        const float a[4][4] = {{v0.x, v1.x, v2.x, v3.x}, {v0.y, v1.y, v2.y, v3.y},
                               {v0.z, v1.z, v2.z, v3.z}, {v0.w, v1.w, v2.w, v3.w}};
        #pragma unroll
        for (int j = 0; j < 4; ++j) {
            const int tb = tbv[j];
            const float4 g = *(const float4*)G4[tb];
            const float d0 = a[j][0] - g.x;
            const float d1 = a[j][1] - g.y;
            const float d2 = a[j][2] - g.z;
            const float d3 = a[j][3] - g.w;
            const float dd = sqrtf(d0 * d0 + d1 * d1 + d2 * d2 + d3 * d3) - 0.5f;
            const float r = fmaxf(dd, 0.0f);
            const float lp = log1pf(r * r);
            #pragma unroll
            for (int t = 1; t < 16; ++t) isum[t - 1] += (tb == t) ? lp : 0.0f;
        }
    }

    #pragma unroll
    for (int k = 0; k < 15; ++k) isum[k] = wave_sum_f(isum[k]);

    __shared__ float iw[4][15];
    if (lane == 63) {
        #pragma unroll
        for (int k = 0; k < 15; ++k) iw[w][k] = isum[k];
    }
    __syncthreads();
    if (tid < 15) {
        ws[WS_ISUM_OFF + (size_t)(s * NB + b) * 16 + tid] =
            (iw[0][tid] + iw[1][tid]) + (iw[2][tid] + iw[3][tid]);
    }
    __syncthreads();
}

__device__ __forceinline__ void phase_final(const float* __restrict__ ws,
                                            float* __restrict__ out,
                                            int s, int tid) {
    if (tid >= 16) return;
    const int t = tid;             // bin index - 1; lane 15 inactive
    float kc = 0.0f, tc = 0.0f, is = 0.0f;
    if (t < 15) {
        #pragma unroll
        for (int pb = 0; pb < NB; ++pb) {
            const float* st = ws + WS_STATS_OFF + (size_t)(s * NB + pb) * SP_F;
            kc += st[t];
            tc += st[75 + t];
            is += ws[WS_ISUM_OFF + (size_t)(s * NB + pb) * 16 + t];
        }
    }
    const bool valid = (t < 15) && (kc > 0.0f) && (tc > 0.0f);
    float im = valid ? is / tc : 0.0f;
    float nv = valid ? 1.0f : 0.0f;
    #pragma unroll
    for (int m = 8; m >= 1; m >>= 1) {
        im += __shfl_xor(im, m, 16);
        nv += __shfl_xor(nv, m, 16);
    }
    if (t == 0) out[s] = (nv > 0.0f) ? (im / nv) : 0.0f;
}

// ---------------- fused cooperative kernel ----------------

__global__ __launch_bounds__(256) void agg_fused(
        const float* __restrict__ preds,
        const int* __restrict__ targets,
        float* __restrict__ ws,
        float* __restrict__ out) {
    const int bid = blockIdx.x;        // 1-D grid, 512 blocks
    const int s = bid >> 4;
    const int b = bid & (NB - 1);
    const int tid = threadIdx.x;

    phase_stats(preds, targets, ws, s, b, tid);

    cg::this_grid().sync();

    __shared__ __align__(16) float G4[16][4];
    compute_G(ws, s, tid, G4);
    phase_loss(preds, targets, ws, s, b, tid, G4);

    cg::this_grid().sync();

    if (b == 0) phase_final(ws, out, s, tid);
}

// ---------------- fallback kernels (R7-proven path) ----------------

__global__ __launch_bounds__(256) void k_stats(
        const float* __restrict__ preds, const int* __restrict__ targets,
        float* __restrict__ ws) {
    phase_stats(preds, targets, ws, blockIdx.y, blockIdx.x, threadIdx.x);
}

__global__ __launch_bounds__(256) void k_loss(
        const float* __restrict__ preds, const int* __restrict__ targets,
        float* __restrict__ ws) {
    __shared__ __align__(16) float G4[16][4];
    compute_G(ws, blockIdx.y, threadIdx.x, G4);
    phase_loss(preds, targets, ws, blockIdx.y, blockIdx.x, threadIdx.x, G4);
}

__global__ __launch_bounds__(64) void k_final(
        const float* __restrict__ ws, float* __restrict__ out) {
    phase_final(ws, out, blockIdx.x, threadIdx.x);
}

extern "C" void kernel_launch(void* const* d_in, const int* in_sizes, int n_in,
                              void* d_out, int out_size, void* d_ws, size_t ws_size,
                              hipStream_t stream) {
    const float* preds = (const float*)d_in[0];
    const int* targets = (const int*)d_in[1];
    float* out = (float*)d_out;
    float* ws = (float*)d_ws;

    void* args[] = {(void*)&preds, (void*)&targets, (void*)&ws, (void*)&out};
    hipError_t err = hipLaunchCooperativeKernel((void*)agg_fused,
                                                dim3(NS * NB), dim3(256),
                                                args, 0, stream);
    if (err != hipSuccess) {
        // deterministic fallback: proven 3-kernel path
        dim3 grid(NB, NS);
        k_stats<<<grid, 256, 0, stream>>>(preds, targets, ws);
        k_loss<<<grid, 256, 0, stream>>>(preds, targets, ws);
        k_final<<<NS, 64, 0, stream>>>(ws, out);
    }
}

// Round 10
// 53.778 us; speedup vs baseline: 2.4055x; 2.4055x over previous
//
#include <hip/hip_runtime.h>
#include <hip/hip_bf16.h>

// AggregationLoss. preds [32,6,256,256] f32, targets [32,2,256,256] i32.
// sim = preds[:,2:6]; text = targets[:,0]; kernel = targets[:,1]; MAX_T=16.
// Per sample: G[t] = mean of sim over kernel==t; per-pixel
// loss = log1p(max(||sim_p - G[text_p]|| - 0.5, 0)^2); per-instance mean over
// text==t for valid t (t>=1, k_cnt>0, t_cnt>0); output = mean over valid.
//
// R10: TWO kernels. R9 lesson: grid.sync costs ~40us @512 blocks -> kernel
// boundaries ARE the cheap grid barrier. Changes vs R7 (43.8us best):
//  - finalize folded into loss kernel as per-sample last-block tail
//    (threadfence + atomic counter; counter zeroed by K1 same call)
//  - K2 hoists pixel loads into registers BEFORE the G re-reduction so the
//    serial 32x90 partial reduce hides under global-load latency
// Kept: register accumulators (R3), DPP wave-reduce (R7), packed int counts,
// NO launch_bounds min-waves (R6 spill lesson), no coop launch (R9 lesson).

#define P_PIX 65536
#define NS 32
#define NB 32              // blocks per sample; grid = 1024 = 4 blocks/CU
#define SP_F 96            // stats partial: kcnt[0..14] ksum[15..74] tcnt[75..89]
#define WS_STATS_OFF 0
#define WS_ISUM_OFF (NS * NB * SP_F)          // isum partials: [NS][NB][16]
#define WS_CNT_OFF (WS_ISUM_OFF + NS * NB * 16)  // int counters: [NS]

// ---- DPP wave(64) sum: result lands in lane 63 (R7 proven) ----
template <int CTRL, int RM>
__device__ __forceinline__ float dpp_mov_f(float v) {
    return __int_as_float(
        __builtin_amdgcn_update_dpp(0, __float_as_int(v), CTRL, RM, 0xf, true));
}
template <int CTRL, int RM>
__device__ __forceinline__ int dpp_mov_i(int v) {
    return __builtin_amdgcn_update_dpp(0, v, CTRL, RM, 0xf, true);
}
__device__ __forceinline__ float wave_sum_f(float v) {
    v += dpp_mov_f<0x111, 0xf>(v);   // row_shr:1
    v += dpp_mov_f<0x112, 0xf>(v);   // row_shr:2
    v += dpp_mov_f<0x114, 0xf>(v);   // row_shr:4
    v += dpp_mov_f<0x118, 0xf>(v);   // row_shr:8
    v += dpp_mov_f<0x142, 0xa>(v);   // row_bcast15
    v += dpp_mov_f<0x143, 0xc>(v);   // row_bcast31 -> lane63 = total
    return v;
}
__device__ __forceinline__ int wave_sum_i(int v) {
    v += dpp_mov_i<0x111, 0xf>(v);
    v += dpp_mov_i<0x112, 0xf>(v);
    v += dpp_mov_i<0x114, 0xf>(v);
    v += dpp_mov_i<0x118, 0xf>(v);
    v += dpp_mov_i<0x142, 0xa>(v);
    v += dpp_mov_i<0x143, 0xc>(v);
    return v;
}

__global__ __launch_bounds__(256) void agg_stats_kernel(
        const float* __restrict__ preds,
        const int* __restrict__ targets,
        float* __restrict__ ws) {
    const int s = blockIdx.y;
    const int b = blockIdx.x;
    const int tid = threadIdx.x;
    const int lane = tid & 63;
    const int w = tid >> 6;

    // reset K2's per-sample finalize counter (K1 completes before K2 starts)
    if (b == 0 && tid == 0) ((int*)ws)[WS_CNT_OFF + s] = 0;

    float ksum[60];
    #pragma unroll
    for (int k = 0; k < 60; ++k) ksum[k] = 0.0f;
    int cnt[15];               // kcnt low16 | tcnt high16 (block-local <= 2048)
    #pragma unroll
    for (int k = 0; k < 15; ++k) cnt[k] = 0;

    const float* sim  = preds + (size_t)s * 6 * P_PIX + 2 * (size_t)P_PIX;
    const int*   text = targets + (size_t)s * 2 * P_PIX;
    const int*   kern = text + P_PIX;

    #pragma unroll
    for (int it = 0; it < 2; ++it) {
        const int p4 = b * 512 + it * 256 + tid;    // float4 index
        const int4   tb4 = ((const int4*)text)[p4];
        const int4   kb4 = ((const int4*)kern)[p4];
        const float4 v0 = ((const float4*)(sim))[p4];
        const float4 v1 = ((const float4*)(sim + P_PIX))[p4];
        const float4 v2 = ((const float4*)(sim + 2 * P_PIX))[p4];
        const float4 v3 = ((const float4*)(sim + 3 * P_PIX))[p4];
        const int tbv[4] = {tb4.x, tb4.y, tb4.z, tb4.w};
        const int kbv[4] = {kb4.x, kb4.y, kb4.z, kb4.w};
        const float a[4][4] = {{v0.x, v1.x, v2.x, v3.x}, {v0.y, v1.y, v2.y, v3.y},
                               {v0.z, v1.z, v2.z, v3.z}, {v0.w, v1.w, v2.w, v3.w}};
        #pragma unroll
        for (int j = 0; j < 4; ++j) {
            const int kb = kbv[j], tb = tbv[j];
            #pragma unroll
            for (int t = 1; t < 16; ++t) {
                const bool pk = (kb == t);
                cnt[t - 1] += (pk ? 1 : 0) + ((tb == t) ? 0x10000 : 0);
                const float m = pk ? 1.0f : 0.0f;
                #pragma unroll
                for (int c = 0; c < 4; ++c)
                    ksum[(t - 1) * 4 + c] = fmaf(m, a[j][c], ksum[(t - 1) * 4 + c]);
            }
        }
    }

    // ---- wave reduce via DPP (VALU pipe), lane 63 holds wave totals ----
    #pragma unroll
    for (int k = 0; k < 60; ++k) ksum[k] = wave_sum_f(ksum[k]);
    #pragma unroll
    for (int k = 0; k < 15; ++k) cnt[k] = wave_sum_i(cnt[k]);

    __shared__ float wsum[4][60];
    __shared__ int   wcnt[4][15];
    if (lane == 63) {
        #pragma unroll
        for (int k = 0; k < 60; ++k) wsum[w][k] = ksum[k];
        #pragma unroll
        for (int k = 0; k < 15; ++k) wcnt[w][k] = cnt[k];
    }
    __syncthreads();

    float* part = ws + WS_STATS_OFF + (size_t)(s * NB + b) * SP_F;
    if (tid < 60) {
        part[15 + tid] = (wsum[0][tid] + wsum[1][tid]) + (wsum[2][tid] + wsum[3][tid]);
    } else if (tid >= 64 && tid < 79) {
        const int k = tid - 64;
        const int ctot = (wcnt[0][k] + wcnt[1][k]) + (wcnt[2][k] + wcnt[3][k]);
        part[k] = (float)(ctot & 0xffff);
        part[75 + k] = (float)(((unsigned)ctot) >> 16);
    }
}

__global__ __launch_bounds__(256) void agg_loss_final_kernel(
        const float* __restrict__ preds,
        const int* __restrict__ targets,
        float* __restrict__ ws,
        float* __restrict__ out) {
    const int s = blockIdx.y;
    const int b = blockIdx.x;
    const int tid = threadIdx.x;
    const int lane = tid & 63;
    const int w = tid >> 6;

    const float* sim  = preds + (size_t)s * 6 * P_PIX + 2 * (size_t)P_PIX;
    const int*   text = targets + (size_t)s * 2 * P_PIX;

    // ---- issue ALL pixel loads first (independent of G) ----
    int4   tb4[2];
    float4 v0[2], v1[2], v2[2], v3[2];
    #pragma unroll
    for (int it = 0; it < 2; ++it) {
        const int p4 = b * 512 + it * 256 + tid;
        tb4[it] = ((const int4*)text)[p4];
        v0[it] = ((const float4*)(sim))[p4];
        v1[it] = ((const float4*)(sim + P_PIX))[p4];
        v2[it] = ((const float4*)(sim + 2 * P_PIX))[p4];
        v3[it] = ((const float4*)(sim + 3 * P_PIX))[p4];
    }

    // ---- G = ksum / max(kcnt,1), reduced over this sample's partials ----
    __shared__ float tmp[90];
    __shared__ __align__(16) float G4[16][4];   // G4[0] = 0 (background dummy)
    if (tid < 90) {
        const float* base = ws + WS_STATS_OFF + (size_t)s * NB * SP_F + tid;
        float v = 0.0f;
        #pragma unroll 8
        for (int pb = 0; pb < NB; ++pb) v += base[pb * SP_F];
        tmp[tid] = v;
    }
    __syncthreads();
    if (tid < 60) G4[1 + (tid >> 2)][tid & 3] = tmp[15 + tid] / fmaxf(tmp[tid >> 2], 1.0f);
    if (tid >= 64 && tid < 68) G4[0][tid - 64] = 0.0f;
    __syncthreads();

    // ---- loss from registers ----
    float isum[15];
    #pragma unroll
    for (int k = 0; k < 15; ++k) isum[k] = 0.0f;

    #pragma unroll
    for (int it = 0; it < 2; ++it) {
        const int tbv[4] = {tb4[it].x, tb4[it].y, tb4[it].z, tb4[it].w};
        const float a[4][4] = {
            {v0[it].x, v1[it].x, v2[it].x, v3[it].x},
            {v0[it].y, v1[it].y, v2[it].y, v3[it].y},
            {v0[it].z, v1[it].z, v2[it].z, v3[it].z},
            {v0[it].w, v1[it].w, v2[it].w, v3[it].w}};
        #pragma unroll
        for (int j = 0; j < 4; ++j) {
            const int tb = tbv[j];
            const float4 g = *(const float4*)G4[tb];
            const float d0 = a[j][0] - g.x;
            const float d1 = a[j][1] - g.y;
            const float d2 = a[j][2] - g.z;
            const float d3 = a[j][3] - g.w;
            const float dd = sqrtf(d0 * d0 + d1 * d1 + d2 * d2 + d3 * d3) - 0.5f;
            const float r = fmaxf(dd, 0.0f);
            const float lp = log1pf(r * r);
            #pragma unroll
            for (int t = 1; t < 16; ++t) isum[t - 1] += (tb == t) ? lp : 0.0f;
        }
    }

    #pragma unroll
    for (int k = 0; k < 15; ++k) isum[k] = wave_sum_f(isum[k]);

    __shared__ float iw[4][15];
    if (lane == 63) {
        #pragma unroll
        for (int k = 0; k < 15; ++k) iw[w][k] = isum[k];
    }
    __syncthreads();
    if (tid < 15) {
        ws[WS_ISUM_OFF + (size_t)(s * NB + b) * 16 + tid] =
            (iw[0][tid] + iw[1][tid]) + (iw[2][tid] + iw[3][tid]);
    }

    // ---- per-sample last-block finalize (threadfence + counter) ----
    __shared__ int amLast;
    __syncthreads();
    if (tid == 0) {
        __threadfence();
        const int old = atomicAdd(&((int*)ws)[WS_CNT_OFF + s], 1);
        amLast = (old == NB - 1) ? 1 : 0;
    }
    __syncthreads();
    if (amLast && tid < 16) {
        __threadfence();               // acquire: see all blocks' partials
        const int t = tid;             // bin index - 1; lane 15 inactive
        float kc = 0.0f, tc = 0.0f, is = 0.0f;
        if (t < 15) {
            #pragma unroll 8
            for (int pb = 0; pb < NB; ++pb) {
                const float* st = ws + WS_STATS_OFF + (size_t)(s * NB + pb) * SP_F;
                kc += st[t];
                tc += st[75 + t];
                is += ws[WS_ISUM_OFF + (size_t)(s * NB + pb) * 16 + t];
            }
        }
        const bool valid = (t < 15) && (kc > 0.0f) && (tc > 0.0f);
        float im = valid ? is / tc : 0.0f;
        float nv = valid ? 1.0f : 0.0f;
        #pragma unroll
        for (int m = 8; m >= 1; m >>= 1) {
            im += __shfl_xor(im, m, 16);
            nv += __shfl_xor(nv, m, 16);
        }
        if (t == 0) out[s] = (nv > 0.0f) ? (im / nv) : 0.0f;
    }
}

extern "C" void kernel_launch(void* const* d_in, const int* in_sizes, int n_in,
                              void* d_out, int out_size, void* d_ws, size_t ws_size,
                              hipStream_t stream) {
    const float* preds = (const float*)d_in[0];
    const int* targets = (const int*)d_in[1];
    float* out = (float*)d_out;
    float* ws = (float*)d_ws;

    dim3 grid(NB, NS);
    agg_stats_kernel<<<grid, 256, 0, stream>>>(preds, targets, ws);
    agg_loss_final_kernel<<<grid, 256, 0, stream>>>(preds, targets, ws, out);
}

// Round 11
// 37.265 us; speedup vs baseline: 3.4714x; 1.4431x over previous
//
#include <hip/hip_runtime.h>
#include <hip/hip_bf16.h>

// AggregationLoss. preds [32,6,256,256] f32, targets [32,2,256,256] i32.
// sim = preds[:,2:6]; text = targets[:,0]; kernel = targets[:,1]; MAX_T=16.
// Per sample: G[t] = mean of sim over kernel==t; per-pixel
// loss = log1p(max(||sim_p - G[text_p]|| - 0.5, 0)^2); per-instance mean over
// text==t for valid t (t>=1, k_cnt>0, t_cnt>0); output = mean over valid.
//
// R11: 3 kernels (R7 structure, 43.8us best). New: K2 uses the LINEARITY of
// the final reduction: out[s] = sum_p lp_p * w[text_p] / n_valid with
// w[t] = valid ? 1/t_cnt[t] : 0. So K2 has NO 15-bin isum loop - one LDS
// w-lookup + one fma per pixel, single-float epilogue. K2's b==0 block also
// stores scale[s] = 1/n_valid (one ballot per block - NOT per pixel, R5).
// K1 = R7 verbatim. No atomics/fences (R10 lesson), no min-waves (R6),
// no coop (R9), register accumulators + DPP reduce (R3/R7).

#define P_PIX 65536
#define NS 32
#define NB 32              // blocks per sample; grid = 1024 = 4 blocks/CU
#define SP_F 96            // stats partial: kcnt[0..14] ksum[15..74] tcnt[75..89]
#define WS_STATS_OFF 0
#define WS_LP_OFF (NS * NB * SP_F)        // loss partials: [NS][NB] floats
#define WS_SC_OFF (WS_LP_OFF + NS * NB)   // scale (1/n_valid): [NS] floats

// ---- DPP wave(64) sum: result lands in lane 63 (R7 proven) ----
template <int CTRL, int RM>
__device__ __forceinline__ float dpp_mov_f(float v) {
    return __int_as_float(
        __builtin_amdgcn_update_dpp(0, __float_as_int(v), CTRL, RM, 0xf, true));
}
template <int CTRL, int RM>
__device__ __forceinline__ int dpp_mov_i(int v) {
    return __builtin_amdgcn_update_dpp(0, v, CTRL, RM, 0xf, true);
}
__device__ __forceinline__ float wave_sum_f(float v) {
    v += dpp_mov_f<0x111, 0xf>(v);   // row_shr:1
    v += dpp_mov_f<0x112, 0xf>(v);   // row_shr:2
    v += dpp_mov_f<0x114, 0xf>(v);   // row_shr:4
    v += dpp_mov_f<0x118, 0xf>(v);   // row_shr:8
    v += dpp_mov_f<0x142, 0xa>(v);   // row_bcast15
    v += dpp_mov_f<0x143, 0xc>(v);   // row_bcast31 -> lane63 = total
    return v;
}
__device__ __forceinline__ int wave_sum_i(int v) {
    v += dpp_mov_i<0x111, 0xf>(v);
    v += dpp_mov_i<0x112, 0xf>(v);
    v += dpp_mov_i<0x114, 0xf>(v);
    v += dpp_mov_i<0x118, 0xf>(v);
    v += dpp_mov_i<0x142, 0xa>(v);
    v += dpp_mov_i<0x143, 0xc>(v);
    return v;
}

// ---------------- K1: segment stats (R7 verbatim) ----------------

__global__ __launch_bounds__(256) void agg_stats_kernel(
        const float* __restrict__ preds,
        const int* __restrict__ targets,
        float* __restrict__ ws) {
    const int s = blockIdx.y;
    const int b = blockIdx.x;
    const int tid = threadIdx.x;
    const int lane = tid & 63;
    const int w = tid >> 6;

    float ksum[60];
    #pragma unroll
    for (int k = 0; k < 60; ++k) ksum[k] = 0.0f;
    int cnt[15];               // kcnt low16 | tcnt high16 (block-local <= 2048)
    #pragma unroll
    for (int k = 0; k < 15; ++k) cnt[k] = 0;

    const float* sim  = preds + (size_t)s * 6 * P_PIX + 2 * (size_t)P_PIX;
    const int*   text = targets + (size_t)s * 2 * P_PIX;
    const int*   kern = text + P_PIX;

    #pragma unroll
    for (int it = 0; it < 2; ++it) {
        const int p4 = b * 512 + it * 256 + tid;    // float4 index
        const int4   tb4 = ((const int4*)text)[p4];
        const int4   kb4 = ((const int4*)kern)[p4];
        const float4 v0 = ((const float4*)(sim))[p4];
        const float4 v1 = ((const float4*)(sim + P_PIX))[p4];
        const float4 v2 = ((const float4*)(sim + 2 * P_PIX))[p4];
        const float4 v3 = ((const float4*)(sim + 3 * P_PIX))[p4];
        const int tbv[4] = {tb4.x, tb4.y, tb4.z, tb4.w};
        const int kbv[4] = {kb4.x, kb4.y, kb4.z, kb4.w};
        const float a[4][4] = {{v0.x, v1.x, v2.x, v3.x}, {v0.y, v1.y, v2.y, v3.y},
                               {v0.z, v1.z, v2.z, v3.z}, {v0.w, v1.w, v2.w, v3.w}};
        #pragma unroll
        for (int j = 0; j < 4; ++j) {
            const int kb = kbv[j], tb = tbv[j];
            #pragma unroll
            for (int t = 1; t < 16; ++t) {
                const bool pk = (kb == t);
                cnt[t - 1] += (pk ? 1 : 0) + ((tb == t) ? 0x10000 : 0);
                const float m = pk ? 1.0f : 0.0f;
                #pragma unroll
                for (int c = 0; c < 4; ++c)
                    ksum[(t - 1) * 4 + c] = fmaf(m, a[j][c], ksum[(t - 1) * 4 + c]);
            }
        }
    }

    #pragma unroll
    for (int k = 0; k < 60; ++k) ksum[k] = wave_sum_f(ksum[k]);
    #pragma unroll
    for (int k = 0; k < 15; ++k) cnt[k] = wave_sum_i(cnt[k]);

    __shared__ float wsum[4][60];
    __shared__ int   wcnt[4][15];
    if (lane == 63) {
        #pragma unroll
        for (int k = 0; k < 60; ++k) wsum[w][k] = ksum[k];
        #pragma unroll
        for (int k = 0; k < 15; ++k) wcnt[w][k] = cnt[k];
    }
    __syncthreads();

    float* part = ws + WS_STATS_OFF + (size_t)(s * NB + b) * SP_F;
    if (tid < 60) {
        part[15 + tid] = (wsum[0][tid] + wsum[1][tid]) + (wsum[2][tid] + wsum[3][tid]);
    } else if (tid >= 64 && tid < 79) {
        const int k = tid - 64;
        const int ctot = (wcnt[0][k] + wcnt[1][k]) + (wcnt[2][k] + wcnt[3][k]);
        part[k] = (float)(ctot & 0xffff);
        part[75 + k] = (float)(((unsigned)ctot) >> 16);
    }
}

// ---------------- K2: weighted loss (linearity trick) ----------------

__global__ __launch_bounds__(256) void agg_loss_kernel(
        const float* __restrict__ preds,
        const int* __restrict__ targets,
        float* __restrict__ ws) {
    const int s = blockIdx.y;
    const int b = blockIdx.x;
    const int tid = threadIdx.x;
    const int lane = tid & 63;
    const int w = tid >> 6;

    __shared__ float tmp[90];
    __shared__ __align__(16) float4 G4[16];   // G4[0] = 0 (background dummy)
    __shared__ float w16[16];                 // w[t] = valid ? 1/t_cnt : 0
    __shared__ float ip[4];

    // reduce this sample's NB stats partials
    if (tid < 90) {
        const float* base = ws + WS_STATS_OFF + (size_t)s * NB * SP_F + tid;
        float v = 0.0f;
        #pragma unroll 8
        for (int pb = 0; pb < NB; ++pb) v += base[pb * SP_F];
        tmp[tid] = v;
    }
    __syncthreads();
    if (tid < 60) ((float*)G4)[4 + tid] = tmp[15 + tid] / fmaxf(tmp[tid >> 2], 1.0f);
    if (tid >= 64 && tid < 68) ((float*)G4)[tid - 64] = 0.0f;
    if (tid < 16) {
        if (tid == 15) {
            w16[0] = 0.0f;
        } else {
            const float kc = tmp[tid];
            const float tc = tmp[75 + tid];
            w16[tid + 1] = (kc > 0.0f && tc > 0.0f) ? 1.0f / tc : 0.0f;
        }
    }
    // scale[s] = 1/n_valid (wave 0 only; ONE ballot per block)
    if (w == 0) {
        const bool vld = (tid < 15) && (tmp[tid] > 0.0f) && (tmp[75 + tid] > 0.0f);
        const unsigned long long m = __ballot(vld);
        if (b == 0 && tid == 0) {
            const float nv = (float)__popcll(m);
            ws[WS_SC_OFF + s] = (nv > 0.0f) ? 1.0f / nv : 0.0f;
        }
    }
    __syncthreads();

    const float* sim  = preds + (size_t)s * 6 * P_PIX + 2 * (size_t)P_PIX;
    const int*   text = targets + (size_t)s * 2 * P_PIX;

    float racc = 0.0f;
    #pragma unroll
    for (int it = 0; it < 2; ++it) {
        const int p4 = b * 512 + it * 256 + tid;
        const int4   tb4 = ((const int4*)text)[p4];
        const float4 v0 = ((const float4*)(sim))[p4];
        const float4 v1 = ((const float4*)(sim + P_PIX))[p4];
        const float4 v2 = ((const float4*)(sim + 2 * P_PIX))[p4];
        const float4 v3 = ((const float4*)(sim + 3 * P_PIX))[p4];
        const int tbv[4] = {tb4.x, tb4.y, tb4.z, tb4.w};
        const float a[4][4] = {{v0.x, v1.x, v2.x, v3.x}, {v0.y, v1.y, v2.y, v3.y},
                               {v0.z, v1.z, v2.z, v3.z}, {v0.w, v1.w, v2.w, v3.w}};
        #pragma unroll
        for (int j = 0; j < 4; ++j) {
            const int tb = tbv[j];
            const float4 g = G4[tb];
            const float wv = w16[tb];
            const float d0 = a[j][0] - g.x;
            const float d1 = a[j][1] - g.y;
            const float d2 = a[j][2] - g.z;
            const float d3 = a[j][3] - g.w;
            const float dd = sqrtf(d0 * d0 + d1 * d1 + d2 * d2 + d3 * d3) - 0.5f;
            const float r = fmaxf(dd, 0.0f);
            const float lp = log1pf(r * r);
            racc = fmaf(lp, wv, racc);
        }
    }

    racc = wave_sum_f(racc);
    if (lane == 63) ip[w] = racc;
    __syncthreads();
    if (tid == 0)
        ws[WS_LP_OFF + (size_t)s * NB + b] = (ip[0] + ip[1]) + (ip[2] + ip[3]);
}

// ---------------- K3: per-sample sum of 32 partials x scale ----------------

__global__ __launch_bounds__(64) void agg_final_kernel(
        const float* __restrict__ ws, float* __restrict__ out) {
    const int s = blockIdx.x;
    const int tid = threadIdx.x;
    float v = (tid < NB) ? ws[WS_LP_OFF + (size_t)s * NB + tid] : 0.0f;
    #pragma unroll
    for (int off = 32; off >= 1; off >>= 1) v += __shfl_down(v, off);
    if (tid == 0) out[s] = v * ws[WS_SC_OFF + s];
}

extern "C" void kernel_launch(void* const* d_in, const int* in_sizes, int n_in,
                              void* d_out, int out_size, void* d_ws, size_t ws_size,
                              hipStream_t stream) {
    const float* preds = (const float*)d_in[0];
    const int* targets = (const int*)d_in[1];
    float* out = (float*)d_out;
    float* ws = (float*)d_ws;

    dim3 grid(NB, NS);
    agg_stats_kernel<<<grid, 256, 0, stream>>>(preds, targets, ws);
    agg_loss_kernel<<<grid, 256, 0, stream>>>(preds, targets, ws);
    agg_final_kernel<<<NS, 64, 0, stream>>>(ws, out);
}

// Round 12
// 32.968 us; speedup vs baseline: 3.9240x; 1.1304x over previous
//
#include <hip/hip_runtime.h>
#include <hip/hip_bf16.h>

// AggregationLoss. preds [32,6,256,256] f32, targets [32,2,256,256] i32.
// sim = preds[:,2:6]; text = targets[:,0]; kernel = targets[:,1]; MAX_T=16.
// Per sample: G[t] = mean of sim over kernel==t; per-pixel
// loss = log1p(max(||sim_p - G[text_p]|| - 0.5, 0)^2); per-instance mean over
// text==t for valid t (t>=1, k_cnt>0, t_cnt>0); output = mean over valid.
//
// R12 = R11 (37.3us best) with ONE change: K1 counts via bit-sliced packed
// counters (kp4 += 1ull << 4*kb; 4-bit fields, <=8 px/thread so no overflow;
// expand 4->8->16-bit fields once at the end) instead of the 15-bin
// cmp/sel/add loop. Removes ~50 VALU ops/px (~35% of K1's VALU).
// Kept verbatim: ksum masked-FMA loop, DPP wave-reduce (R7), K2 linearity
// trick (R11), K3, no atomics/fences (R10), no coop (R9), no min-waves (R6).

#define P_PIX 65536
#define NS 32
#define NB 32              // blocks per sample; grid = 1024 = 4 blocks/CU
#define SP_F 96            // stats partial: kcnt[0..14] ksum[15..74] tcnt[75..89]
#define WS_STATS_OFF 0
#define WS_LP_OFF (NS * NB * SP_F)        // loss partials: [NS][NB] floats
#define WS_SC_OFF (WS_LP_OFF + NS * NB)   // scale (1/n_valid): [NS] floats

// ---- DPP wave(64) sum: result lands in lane 63 (R7 proven) ----
template <int CTRL, int RM>
__device__ __forceinline__ float dpp_mov_f(float v) {
    return __int_as_float(
        __builtin_amdgcn_update_dpp(0, __float_as_int(v), CTRL, RM, 0xf, true));
}
template <int CTRL, int RM>
__device__ __forceinline__ int dpp_mov_i(int v) {
    return __builtin_amdgcn_update_dpp(0, v, CTRL, RM, 0xf, true);
}
__device__ __forceinline__ float wave_sum_f(float v) {
    v += dpp_mov_f<0x111, 0xf>(v);   // row_shr:1
    v += dpp_mov_f<0x112, 0xf>(v);   // row_shr:2
    v += dpp_mov_f<0x114, 0xf>(v);   // row_shr:4
    v += dpp_mov_f<0x118, 0xf>(v);   // row_shr:8
    v += dpp_mov_f<0x142, 0xa>(v);   // row_bcast15
    v += dpp_mov_f<0x143, 0xc>(v);   // row_bcast31 -> lane63 = total
    return v;
}
__device__ __forceinline__ unsigned int wave_sum_u(unsigned int v) {
    v += (unsigned int)dpp_mov_i<0x111, 0xf>((int)v);
    v += (unsigned int)dpp_mov_i<0x112, 0xf>((int)v);
    v += (unsigned int)dpp_mov_i<0x114, 0xf>((int)v);
    v += (unsigned int)dpp_mov_i<0x118, 0xf>((int)v);
    v += (unsigned int)dpp_mov_i<0x142, 0xa>((int)v);
    v += (unsigned int)dpp_mov_i<0x143, 0xc>((int)v);
    return v;
}

// ---------------- K1: segment stats (bit-sliced counters) ----------------

__global__ __launch_bounds__(256) void agg_stats_kernel(
        const float* __restrict__ preds,
        const int* __restrict__ targets,
        float* __restrict__ ws) {
    const int s = blockIdx.y;
    const int b = blockIdx.x;
    const int tid = threadIdx.x;
    const int lane = tid & 63;
    const int w = tid >> 6;

    float ksum[60];
    #pragma unroll
    for (int k = 0; k < 60; ++k) ksum[k] = 0.0f;
    // bit-sliced counters: bin b at bits [4b..4b+3]; 8 px/thread <= 15 cap
    unsigned long long kp4 = 0ull, tp4 = 0ull;

    const float* sim  = preds + (size_t)s * 6 * P_PIX + 2 * (size_t)P_PIX;
    const int*   text = targets + (size_t)s * 2 * P_PIX;
    const int*   kern = text + P_PIX;

    #pragma unroll
    for (int it = 0; it < 2; ++it) {
        const int p4 = b * 512 + it * 256 + tid;    // float4 index
        const int4   tb4 = ((const int4*)text)[p4];
        const int4   kb4 = ((const int4*)kern)[p4];
        const float4 v0 = ((const float4*)(sim))[p4];
        const float4 v1 = ((const float4*)(sim + P_PIX))[p4];
        const float4 v2 = ((const float4*)(sim + 2 * P_PIX))[p4];
        const float4 v3 = ((const float4*)(sim + 3 * P_PIX))[p4];
        const int tbv[4] = {tb4.x, tb4.y, tb4.z, tb4.w};
        const int kbv[4] = {kb4.x, kb4.y, kb4.z, kb4.w};
        const float a[4][4] = {{v0.x, v1.x, v2.x, v3.x}, {v0.y, v1.y, v2.y, v3.y},
                               {v0.z, v1.z, v2.z, v3.z}, {v0.w, v1.w, v2.w, v3.w}};
        #pragma unroll
        for (int j = 0; j < 4; ++j) {
            const int kb = kbv[j], tb = tbv[j];
            kp4 += 1ull << (4 * kb);
            tp4 += 1ull << (4 * tb);
            #pragma unroll
            for (int t = 1; t < 16; ++t) {
                const float m = (kb == t) ? 1.0f : 0.0f;
                #pragma unroll
                for (int c = 0; c < 4; ++c)
                    ksum[(t - 1) * 4 + c] = fmaf(m, a[j][c], ksum[(t - 1) * 4 + c]);
            }
        }
    }

    // expand 4-bit fields -> 16-bit fields (8 u32 per counter type)
    // bin b: u64 u = (b&1)*2 + ((b>>1)&1)  [e0,e1,o0,o1 order below is
    // u=0:e0, u=1:e1, u=2:o0, u=3:o1]; 16-bit slot f = b>>2 within u64.
    const unsigned long long M4 = 0x0F0F0F0F0F0F0F0Full;
    const unsigned long long M8 = 0x00FF00FF00FF00FFull;
    unsigned int kc[8], tc[8];
    {
        unsigned long long e = kp4 & M4, o = (kp4 >> 4) & M4;
        unsigned long long e0 = e & M8, e1 = (e >> 8) & M8;
        unsigned long long o0 = o & M8, o1 = (o >> 8) & M8;
        kc[0] = (unsigned int)e0; kc[1] = (unsigned int)(e0 >> 32);
        kc[2] = (unsigned int)e1; kc[3] = (unsigned int)(e1 >> 32);
        kc[4] = (unsigned int)o0; kc[5] = (unsigned int)(o0 >> 32);
        kc[6] = (unsigned int)o1; kc[7] = (unsigned int)(o1 >> 32);
    }
    {
        unsigned long long e = tp4 & M4, o = (tp4 >> 4) & M4;
        unsigned long long e0 = e & M8, e1 = (e >> 8) & M8;
        unsigned long long o0 = o & M8, o1 = (o >> 8) & M8;
        tc[0] = (unsigned int)e0; tc[1] = (unsigned int)(e0 >> 32);
        tc[2] = (unsigned int)e1; tc[3] = (unsigned int)(e1 >> 32);
        tc[4] = (unsigned int)o0; tc[5] = (unsigned int)(o0 >> 32);
        tc[6] = (unsigned int)o1; tc[7] = (unsigned int)(o1 >> 32);
    }

    // wave reduce: 16-bit fields sum to <= 64*8=512 -> no overflow
    #pragma unroll
    for (int k = 0; k < 60; ++k) ksum[k] = wave_sum_f(ksum[k]);
    #pragma unroll
    for (int k = 0; k < 8; ++k) { kc[k] = wave_sum_u(kc[k]); tc[k] = wave_sum_u(tc[k]); }

    __shared__ float wsum[4][60];
    __shared__ unsigned int wk[4][8], wt[4][8];
    if (lane == 63) {
        #pragma unroll
        for (int k = 0; k < 60; ++k) wsum[w][k] = ksum[k];
        #pragma unroll
        for (int k = 0; k < 8; ++k) { wk[w][k] = kc[k]; wt[w][k] = tc[k]; }
    }
    __syncthreads();

    float* part = ws + WS_STATS_OFF + (size_t)(s * NB + b) * SP_F;
    if (tid < 60) {
        part[15 + tid] = (wsum[0][tid] + wsum[1][tid]) + (wsum[2][tid] + wsum[3][tid]);
    } else if (tid >= 64 && tid < 94) {
        // 30 threads: k<15 -> kcnt of bin k+1 -> part[k];
        //             k>=15 -> tcnt of bin k-14 -> part[75+k-15]
        const int k = tid - 64;
        const int bin = (k < 15) ? (k + 1) : (k - 14);
        const unsigned int (*src)[8] = (k < 15) ? wk : wt;
        const int u = (bin & 1) * 2 + ((bin >> 1) & 1);     // which u64
        const int f = bin >> 2;                             // 16-bit slot
        const int idx = u * 2 + (f >> 1);                   // which u32
        const int sh = (f & 1) * 16;
        const unsigned int sum = src[0][idx] + src[1][idx] + src[2][idx] + src[3][idx];
        const float val = (float)((sum >> sh) & 0xFFFFu);
        part[(k < 15) ? k : (75 + k - 15)] = val;
    }
}

// ---------------- K2: weighted loss (R11 linearity trick, verbatim) --------

__global__ __launch_bounds__(256) void agg_loss_kernel(
        const float* __restrict__ preds,
        const int* __restrict__ targets,
        float* __restrict__ ws) {
    const int s = blockIdx.y;
    const int b = blockIdx.x;
    const int tid = threadIdx.x;
    const int lane = tid & 63;
    const int w = tid >> 6;

    __shared__ float tmp[90];
    __shared__ __align__(16) float4 G4[16];   // G4[0] = 0 (background dummy)
    __shared__ float w16[16];                 // w[t] = valid ? 1/t_cnt : 0
    __shared__ float ip[4];

    if (tid < 90) {
        const float* base = ws + WS_STATS_OFF + (size_t)s * NB * SP_F + tid;
        float v = 0.0f;
        #pragma unroll 8
        for (int pb = 0; pb < NB; ++pb) v += base[pb * SP_F];
        tmp[tid] = v;
    }
    __syncthreads();
    if (tid < 60) ((float*)G4)[4 + tid] = tmp[15 + tid] / fmaxf(tmp[tid >> 2], 1.0f);
    if (tid >= 64 && tid < 68) ((float*)G4)[tid - 64] = 0.0f;
    if (tid < 16) {
        if (tid == 15) {
            w16[0] = 0.0f;
        } else {
            const float kcv = tmp[tid];
            const float tcv = tmp[75 + tid];
            w16[tid + 1] = (kcv > 0.0f && tcv > 0.0f) ? 1.0f / tcv : 0.0f;
        }
    }
    if (w == 0) {
        const bool vld = (tid < 15) && (tmp[tid] > 0.0f) && (tmp[75 + tid] > 0.0f);
        const unsigned long long m = __ballot(vld);
        if (b == 0 && tid == 0) {
            const float nv = (float)__popcll(m);
            ws[WS_SC_OFF + s] = (nv > 0.0f) ? 1.0f / nv : 0.0f;
        }
    }
    __syncthreads();

    const float* sim  = preds + (size_t)s * 6 * P_PIX + 2 * (size_t)P_PIX;
    const int*   text = targets + (size_t)s * 2 * P_PIX;

    float racc = 0.0f;
    #pragma unroll
    for (int it = 0; it < 2; ++it) {
        const int p4 = b * 512 + it * 256 + tid;
        const int4   tb4 = ((const int4*)text)[p4];
        const float4 v0 = ((const float4*)(sim))[p4];
        const float4 v1 = ((const float4*)(sim + P_PIX))[p4];
        const float4 v2 = ((const float4*)(sim + 2 * P_PIX))[p4];
        const float4 v3 = ((const float4*)(sim + 3 * P_PIX))[p4];
        const int tbv[4] = {tb4.x, tb4.y, tb4.z, tb4.w};
        const float a[4][4] = {{v0.x, v1.x, v2.x, v3.x}, {v0.y, v1.y, v2.y, v3.y},
                               {v0.z, v1.z, v2.z, v3.z}, {v0.w, v1.w, v2.w, v3.w}};
        #pragma unroll
        for (int j = 0; j < 4; ++j) {
            const int tb = tbv[j];
            const float4 g = G4[tb];
            const float wv = w16[tb];
            const float d0 = a[j][0] - g.x;
            const float d1 = a[j][1] - g.y;
            const float d2 = a[j][2] - g.z;
            const float d3 = a[j][3] - g.w;
            const float dd = sqrtf(d0 * d0 + d1 * d1 + d2 * d2 + d3 * d3) - 0.5f;
            const float r = fmaxf(dd, 0.0f);
            const float lp = log1pf(r * r);
            racc = fmaf(lp, wv, racc);
        }
    }

    racc = wave_sum_f(racc);
    if (lane == 63) ip[w] = racc;
    __syncthreads();
    if (tid == 0)
        ws[WS_LP_OFF + (size_t)s * NB + b] = (ip[0] + ip[1]) + (ip[2] + ip[3]);
}

// ---------------- K3: per-sample sum of 32 partials x scale ----------------

__global__ __launch_bounds__(64) void agg_final_kernel(
        const float* __restrict__ ws, float* __restrict__ out) {
    const int s = blockIdx.x;
    const int tid = threadIdx.x;
    float v = (tid < NB) ? ws[WS_LP_OFF + (size_t)s * NB + tid] : 0.0f;
    #pragma unroll
    for (int off = 32; off >= 1; off >>= 1) v += __shfl_down(v, off);
    if (tid == 0) out[s] = v * ws[WS_SC_OFF + s];
}

extern "C" void kernel_launch(void* const* d_in, const int* in_sizes, int n_in,
                              void* d_out, int out_size, void* d_ws, size_t ws_size,
                              hipStream_t stream) {
    const float* preds = (const float*)d_in[0];
    const int* targets = (const int*)d_in[1];
    float* out = (float*)d_out;
    float* ws = (float*)d_ws;

    dim3 grid(NB, NS);
    agg_stats_kernel<<<grid, 256, 0, stream>>>(preds, targets, ws);
    agg_loss_kernel<<<grid, 256, 0, stream>>>(preds, targets, ws);
    agg_final_kernel<<<NS, 64, 0, stream>>>(ws, out);
}

// Round 13
// 30.773 us; speedup vs baseline: 4.2039x; 1.0713x over previous
//
#include <hip/hip_runtime.h>
#include <hip/hip_bf16.h>

// AggregationLoss. preds [32,6,256,256] f32, targets [32,2,256,256] i32.
// sim = preds[:,2:6]; text = targets[:,0]; kernel = targets[:,1]; MAX_T=16.
// Per sample: G[t] = mean of sim over kernel==t; per-pixel
// loss = log1p(max(||sim_p - G[text_p]|| - 0.5, 0)^2); per-instance mean over
// text==t for valid t (t>=1, k_cnt>0, t_cnt>0); output = mean over valid.
//
// R13 = R12 (33.0us) with two K1 changes (K2/K3 verbatim):
//  - ksum as float2 ext-vectors -> v_pk_fma_f32 (VOP3P) halves FMA instrs
//  - K1 NB 32->16 (16 px/thread): DPP-reduce epilogue (~43% of K1 instr
//    stream at 8 px/thread) amortized to ~27%. Counts split into 2 u64
//    halves (8 px each, 4-bit cap 15) merged at 8-bit expansion.
// Calibration (R11->R12): K1 is VALU-issue-bound, ~0.086us per op/px.
// Kept: bit-sliced counts (R12), K2 linearity (R11), DPP reduce (R7),
// no atomics/fences (R10), no coop (R9), no min-waves (R6).

#define P_PIX 65536
#define NS 32
#define NB1 16             // K1 blocks per sample (512 blocks, 16 px/thread)
#define NB2 32             // K2 blocks per sample (1024 blocks, 8 px/thread)
#define SP_F 96            // stats partial: kcnt[0..14] ksum[15..74] tcnt[75..89]
#define WS_STATS_OFF 0
#define WS_LP_OFF (NS * NB1 * SP_F)         // loss partials: [NS][NB2] floats
#define WS_SC_OFF (WS_LP_OFF + NS * NB2)    // scale (1/n_valid): [NS] floats

typedef float v2f __attribute__((ext_vector_type(2)));

// ---- DPP wave(64) sum: result lands in lane 63 (R7 proven) ----
template <int CTRL, int RM>
__device__ __forceinline__ float dpp_mov_f(float v) {
    return __int_as_float(
        __builtin_amdgcn_update_dpp(0, __float_as_int(v), CTRL, RM, 0xf, true));
}
template <int CTRL, int RM>
__device__ __forceinline__ int dpp_mov_i(int v) {
    return __builtin_amdgcn_update_dpp(0, v, CTRL, RM, 0xf, true);
}
__device__ __forceinline__ float wave_sum_f(float v) {
    v += dpp_mov_f<0x111, 0xf>(v);   // row_shr:1
    v += dpp_mov_f<0x112, 0xf>(v);   // row_shr:2
    v += dpp_mov_f<0x114, 0xf>(v);   // row_shr:4
    v += dpp_mov_f<0x118, 0xf>(v);   // row_shr:8
    v += dpp_mov_f<0x142, 0xa>(v);   // row_bcast15
    v += dpp_mov_f<0x143, 0xc>(v);   // row_bcast31 -> lane63 = total
    return v;
}
__device__ __forceinline__ unsigned int wave_sum_u(unsigned int v) {
    v += (unsigned int)dpp_mov_i<0x111, 0xf>((int)v);
    v += (unsigned int)dpp_mov_i<0x112, 0xf>((int)v);
    v += (unsigned int)dpp_mov_i<0x114, 0xf>((int)v);
    v += (unsigned int)dpp_mov_i<0x118, 0xf>((int)v);
    v += (unsigned int)dpp_mov_i<0x142, 0xa>((int)v);
    v += (unsigned int)dpp_mov_i<0x143, 0xc>((int)v);
    return v;
}

// ---------------- K1: segment stats (pk-fma + bit-sliced counts) ----------

__global__ __launch_bounds__(256) void agg_stats_kernel(
        const float* __restrict__ preds,
        const int* __restrict__ targets,
        float* __restrict__ ws) {
    const int s = blockIdx.y;
    const int b = blockIdx.x;
    const int tid = threadIdx.x;
    const int lane = tid & 63;
    const int w = tid >> 6;

    v2f ksum2[30];             // [bin-1][half]: half 0 = ch{0,1}, 1 = ch{2,3}
    #pragma unroll
    for (int k = 0; k < 30; ++k) ksum2[k] = (v2f){0.0f, 0.0f};
    // bit-sliced counters, two halves (8 px each <= 15 cap per 4-bit field)
    unsigned long long kp[2] = {0ull, 0ull}, tp[2] = {0ull, 0ull};

    const float* sim  = preds + (size_t)s * 6 * P_PIX + 2 * (size_t)P_PIX;
    const int*   text = targets + (size_t)s * 2 * P_PIX;
    const int*   kern = text + P_PIX;

    #pragma unroll
    for (int it = 0; it < 4; ++it) {
        const int p4 = b * 1024 + it * 256 + tid;   // float4 index
        const int4   tb4 = ((const int4*)text)[p4];
        const int4   kb4 = ((const int4*)kern)[p4];
        const float4 v0 = ((const float4*)(sim))[p4];
        const float4 v1 = ((const float4*)(sim + P_PIX))[p4];
        const float4 v2 = ((const float4*)(sim + 2 * P_PIX))[p4];
        const float4 v3 = ((const float4*)(sim + 3 * P_PIX))[p4];
        const int tbv[4] = {tb4.x, tb4.y, tb4.z, tb4.w};
        const int kbv[4] = {kb4.x, kb4.y, kb4.z, kb4.w};
        const v2f a01[4] = {{v0.x, v1.x}, {v0.y, v1.y}, {v0.z, v1.z}, {v0.w, v1.w}};
        const v2f a23[4] = {{v2.x, v3.x}, {v2.y, v3.y}, {v2.z, v3.z}, {v2.w, v3.w}};
        const int h = it >> 1;                       // compile-time after unroll
        #pragma unroll
        for (int j = 0; j < 4; ++j) {
            const int kb = kbv[j], tb = tbv[j];
            kp[h] += 1ull << (4 * kb);
            tp[h] += 1ull << (4 * tb);
            #pragma unroll
            for (int t = 1; t < 16; ++t) {
                const float mm = (kb == t) ? 1.0f : 0.0f;
                const v2f m2 = {mm, mm};
                ksum2[(t - 1) * 2 + 0] = m2 * a01[j] + ksum2[(t - 1) * 2 + 0];
                ksum2[(t - 1) * 2 + 1] = m2 * a23[j] + ksum2[(t - 1) * 2 + 1];
            }
        }
    }

    // expand 4-bit fields -> 16-bit fields (merge the two 8-px halves at the
    // 8-bit stage: nibble sums <= 16 fit in a byte)
    const unsigned long long M4 = 0x0F0F0F0F0F0F0F0Full;
    const unsigned long long M8 = 0x00FF00FF00FF00FFull;
    unsigned int kc[8], tc[8];
    {
        unsigned long long e = (kp[0] & M4) + (kp[1] & M4);
        unsigned long long o = ((kp[0] >> 4) & M4) + ((kp[1] >> 4) & M4);
        unsigned long long e0 = e & M8, e1 = (e >> 8) & M8;
        unsigned long long o0 = o & M8, o1 = (o >> 8) & M8;
        kc[0] = (unsigned int)e0; kc[1] = (unsigned int)(e0 >> 32);
        kc[2] = (unsigned int)e1; kc[3] = (unsigned int)(e1 >> 32);
        kc[4] = (unsigned int)o0; kc[5] = (unsigned int)(o0 >> 32);
        kc[6] = (unsigned int)o1; kc[7] = (unsigned int)(o1 >> 32);
    }
    {
        unsigned long long e = (tp[0] & M4) + (tp[1] & M4);
        unsigned long long o = ((tp[0] >> 4) & M4) + ((tp[1] >> 4) & M4);
        unsigned long long e0 = e & M8, e1 = (e >> 8) & M8;
        unsigned long long o0 = o & M8, o1 = (o >> 8) & M8;
        tc[0] = (unsigned int)e0; tc[1] = (unsigned int)(e0 >> 32);
        tc[2] = (unsigned int)e1; tc[3] = (unsigned int)(e1 >> 32);
        tc[4] = (unsigned int)o0; tc[5] = (unsigned int)(o0 >> 32);
        tc[6] = (unsigned int)o1; tc[7] = (unsigned int)(o1 >> 32);
    }

    // wave reduce: 16-bit fields sum to <= 64*16=1024 -> no overflow
    float ks[60];
    #pragma unroll
    for (int k = 0; k < 30; ++k) { ks[2 * k] = ksum2[k].x; ks[2 * k + 1] = ksum2[k].y; }
    // ks layout: [bin-1][half][elem]: ks[(t-1)*4 + h*2 + e] = channel h*2+e
    #pragma unroll
    for (int k = 0; k < 60; ++k) ks[k] = wave_sum_f(ks[k]);
    #pragma unroll
    for (int k = 0; k < 8; ++k) { kc[k] = wave_sum_u(kc[k]); tc[k] = wave_sum_u(tc[k]); }

    __shared__ float wsum[4][60];
    __shared__ unsigned int wk[4][8], wt[4][8];
    if (lane == 63) {
        #pragma unroll
        for (int k = 0; k < 60; ++k) wsum[w][k] = ks[k];
        #pragma unroll
        for (int k = 0; k < 8; ++k) { wk[w][k] = kc[k]; wt[w][k] = tc[k]; }
    }
    __syncthreads();

    float* part = ws + WS_STATS_OFF + (size_t)(s * NB1 + b) * SP_F;
    if (tid < 60) {
        // ks index == ksum index (t-1)*4 + c since layout matches channels 0..3
        part[15 + tid] = (wsum[0][tid] + wsum[1][tid]) + (wsum[2][tid] + wsum[3][tid]);
    } else if (tid >= 64 && tid < 94) {
        const int k = tid - 64;
        const int bin = (k < 15) ? (k + 1) : (k - 14);
        const unsigned int (*src)[8] = (k < 15) ? wk : wt;
        const int u = (bin & 1) * 2 + ((bin >> 1) & 1);     // which u64
        const int f = bin >> 2;                             // 16-bit slot
        const int idx = u * 2 + (f >> 1);                   // which u32
        const int sh = (f & 1) * 16;
        const unsigned int sum = src[0][idx] + src[1][idx] + src[2][idx] + src[3][idx];
        part[(k < 15) ? k : (75 + k - 15)] = (float)((sum >> sh) & 0xFFFFu);
    }
}

// ---------------- K2: weighted loss (R11 linearity trick, verbatim) --------

__global__ __launch_bounds__(256) void agg_loss_kernel(
        const float* __restrict__ preds,
        const int* __restrict__ targets,
        float* __restrict__ ws) {
    const int s = blockIdx.y;
    const int b = blockIdx.x;
    const int tid = threadIdx.x;
    const int lane = tid & 63;
    const int w = tid >> 6;

    __shared__ float tmp[90];
    __shared__ __align__(16) float4 G4[16];   // G4[0] = 0 (background dummy)
    __shared__ float w16[16];                 // w[t] = valid ? 1/t_cnt : 0
    __shared__ float ip[4];

    if (tid < 90) {
        const float* base = ws + WS_STATS_OFF + (size_t)s * NB1 * SP_F + tid;
        float v = 0.0f;
        #pragma unroll
        for (int pb = 0; pb < NB1; ++pb) v += base[pb * SP_F];
        tmp[tid] = v;
    }
    __syncthreads();
    if (tid < 60) ((float*)G4)[4 + tid] = tmp[15 + tid] / fmaxf(tmp[tid >> 2], 1.0f);
    if (tid >= 64 && tid < 68) ((float*)G4)[tid - 64] = 0.0f;
    if (tid < 16) {
        if (tid == 15) {
            w16[0] = 0.0f;
        } else {
            const float kcv = tmp[tid];
            const float tcv = tmp[75 + tid];
            w16[tid + 1] = (kcv > 0.0f && tcv > 0.0f) ? 1.0f / tcv : 0.0f;
        }
    }
    if (w == 0) {
        const bool vld = (tid < 15) && (tmp[tid] > 0.0f) && (tmp[75 + tid] > 0.0f);
        const unsigned long long m = __ballot(vld);
        if (b == 0 && tid == 0) {
            const float nv = (float)__popcll(m);
            ws[WS_SC_OFF + s] = (nv > 0.0f) ? 1.0f / nv : 0.0f;
        }
    }
    __syncthreads();

    const float* sim  = preds + (size_t)s * 6 * P_PIX + 2 * (size_t)P_PIX;
    const int*   text = targets + (size_t)s * 2 * P_PIX;

    float racc = 0.0f;
    #pragma unroll
    for (int it = 0; it < 2; ++it) {
        const int p4 = b * 512 + it * 256 + tid;
        const int4   tb4 = ((const int4*)text)[p4];
        const float4 v0 = ((const float4*)(sim))[p4];
        const float4 v1 = ((const float4*)(sim + P_PIX))[p4];
        const float4 v2 = ((const float4*)(sim + 2 * P_PIX))[p4];
        const float4 v3 = ((const float4*)(sim + 3 * P_PIX))[p4];
        const int tbv[4] = {tb4.x, tb4.y, tb4.z, tb4.w};
        const float a[4][4] = {{v0.x, v1.x, v2.x, v3.x}, {v0.y, v1.y, v2.y, v3.y},
                               {v0.z, v1.z, v2.z, v3.z}, {v0.w, v1.w, v2.w, v3.w}};
        #pragma unroll
        for (int j = 0; j < 4; ++j) {
            const int tb = tbv[j];
            const float4 g = G4[tb];
            const float wv = w16[tb];
            const float d0 = a[j][0] - g.x;
            const float d1 = a[j][1] - g.y;
            const float d2 = a[j][2] - g.z;
            const float d3 = a[j][3] - g.w;
            const float dd = sqrtf(d0 * d0 + d1 * d1 + d2 * d2 + d3 * d3) - 0.5f;
            const float r = fmaxf(dd, 0.0f);
            const float lp = log1pf(r * r);
            racc = fmaf(lp, wv, racc);
        }
    }

    racc = wave_sum_f(racc);
    if (lane == 63) ip[w] = racc;
    __syncthreads();
    if (tid == 0)
        ws[WS_LP_OFF + (size_t)s * NB2 + b] = (ip[0] + ip[1]) + (ip[2] + ip[3]);
}

// ---------------- K3: per-sample sum of 32 partials x scale ----------------

__global__ __launch_bounds__(64) void agg_final_kernel(
        const float* __restrict__ ws, float* __restrict__ out) {
    const int s = blockIdx.x;
    const int tid = threadIdx.x;
    float v = (tid < NB2) ? ws[WS_LP_OFF + (size_t)s * NB2 + tid] : 0.0f;
    #pragma unroll
    for (int off = 32; off >= 1; off >>= 1) v += __shfl_down(v, off);
    if (tid == 0) out[s] = v * ws[WS_SC_OFF + s];
}

extern "C" void kernel_launch(void* const* d_in, const int* in_sizes, int n_in,
                              void* d_out, int out_size, void* d_ws, size_t ws_size,
                              hipStream_t stream) {
    const float* preds = (const float*)d_in[0];
    const int* targets = (const int*)d_in[1];
    float* out = (float*)d_out;
    float* ws = (float*)d_ws;

    agg_stats_kernel<<<dim3(NB1, NS), 256, 0, stream>>>(preds, targets, ws);
    agg_loss_kernel<<<dim3(NB2, NS), 256, 0, stream>>>(preds, targets, ws);
    agg_final_kernel<<<NS, 64, 0, stream>>>(ws, out);
}

// Round 14
// 24.866 us; speedup vs baseline: 5.2025x; 1.2376x over previous
//
#include <hip/hip_runtime.h>
#include <hip/hip_bf16.h>

// AggregationLoss. preds [32,6,256,256] f32, targets [32,2,256,256] i32.
// sim = preds[:,2:6]; text = targets[:,0]; kernel = targets[:,1]; MAX_T=16.
// Per sample: G[t] = mean of sim over kernel==t; per-pixel
// loss = log1p(max(||sim_p - G[text_p]|| - 0.5, 0)^2); per-instance mean over
// text==t for valid t (t>=1, k_cnt>0, t_cnt>0); output = mean over valid.
//
// R14 = R13 (30.8us) with K1 rewritten: per-THREAD private LDS rows with
// plain (non-atomic) indexed RMW replace the 15-bin masked-FMA loop
// (~75 -> ~12 VALU + 4 DS inst/px). R2's LDS-atomic failure (~200cyc/op)
// does not apply: same-wave DS ops are pipe-ordered, no atomics needed.
// Rows padded to 34 floats -> worst 2-way bank aliasing (free, m136).
// K2: log1pf -> __logf(fma(r,r,1)) (v_log_f32). K3 verbatim.
// Kept: bit-sliced counts (R12), K2 linearity (R11), no atomics/fences
// (R10), no coop (R9), no launch_bounds min-waves (R6).

#define P_PIX 65536
#define NS 32
#define NB1 32             // K1 blocks/sample; 1024 blocks x 128 thr, 16 px/thr
#define NB2 32             // K2 blocks/sample; 1024 blocks x 256 thr, 8 px/thr
#define SP_F 96            // stats partial: kcnt[0..14] ksum[15..74] tcnt[75..89]
#define WS_STATS_OFF 0
#define WS_LP_OFF (NS * NB1 * SP_F)         // loss partials: [NS][NB2] floats
#define WS_SC_OFF (WS_LP_OFF + NS * NB2)    // scale (1/n_valid): [NS] floats

typedef float v2f __attribute__((ext_vector_type(2)));

// ---- DPP wave(64) sum: result lands in lane 63 (R7 proven) ----
template <int CTRL, int RM>
__device__ __forceinline__ float dpp_mov_f(float v) {
    return __int_as_float(
        __builtin_amdgcn_update_dpp(0, __float_as_int(v), CTRL, RM, 0xf, true));
}
template <int CTRL, int RM>
__device__ __forceinline__ int dpp_mov_i(int v) {
    return __builtin_amdgcn_update_dpp(0, v, CTRL, RM, 0xf, true);
}
__device__ __forceinline__ float wave_sum_f(float v) {
    v += dpp_mov_f<0x111, 0xf>(v);
    v += dpp_mov_f<0x112, 0xf>(v);
    v += dpp_mov_f<0x114, 0xf>(v);
    v += dpp_mov_f<0x118, 0xf>(v);
    v += dpp_mov_f<0x142, 0xa>(v);
    v += dpp_mov_f<0x143, 0xc>(v);
    return v;
}
__device__ __forceinline__ unsigned int wave_sum_u(unsigned int v) {
    v += (unsigned int)dpp_mov_i<0x111, 0xf>((int)v);
    v += (unsigned int)dpp_mov_i<0x112, 0xf>((int)v);
    v += (unsigned int)dpp_mov_i<0x114, 0xf>((int)v);
    v += (unsigned int)dpp_mov_i<0x118, 0xf>((int)v);
    v += (unsigned int)dpp_mov_i<0x142, 0xa>((int)v);
    v += (unsigned int)dpp_mov_i<0x143, 0xc>((int)v);
    return v;
}

// ---------------- K1: segment stats (private-LDS scatter) ----------------

#define ROWF 34            // floats per row (16 bins x 2 ch + 2 pad)

__global__ __launch_bounds__(128) void agg_stats_kernel(
        const float* __restrict__ preds,
        const int* __restrict__ targets,
        float* __restrict__ ws) {
    const int s = blockIdx.y;
    const int b = blockIdx.x;
    const int tid = threadIdx.x;      // 0..127
    const int lane = tid & 63;
    const int w = tid >> 6;           // wave 0/1

    // acc[region][row][bin*2 + (ch&1)]: region 0 = ch{0,1}, 1 = ch{2,3}
    __shared__ __align__(16) float acc[2][128][ROWF];     // 34816 B
    {
        float4* a4 = (float4*)acc;    // 2176 float4
        #pragma unroll
        for (int i = 0; i < 17; ++i)
            a4[i * 128 + tid] = make_float4(0.f, 0.f, 0.f, 0.f);
    }
    __syncthreads();

    // bit-sliced counters, two 8-px halves (4-bit fields cap 15)
    unsigned long long kp[2] = {0ull, 0ull}, tp[2] = {0ull, 0ull};

    const float* sim  = preds + (size_t)s * 6 * P_PIX + 2 * (size_t)P_PIX;
    const int*   text = targets + (size_t)s * 2 * P_PIX;
    const int*   kern = text + P_PIX;

    float* row01 = &acc[0][tid][0];
    float* row23 = &acc[1][tid][0];

    #pragma unroll
    for (int it = 0; it < 4; ++it) {
        const int p4 = b * 512 + it * 128 + tid;    // float4 index
        const int4   tb4 = ((const int4*)text)[p4];
        const int4   kb4 = ((const int4*)kern)[p4];
        const float4 v0 = ((const float4*)(sim))[p4];
        const float4 v1 = ((const float4*)(sim + P_PIX))[p4];
        const float4 v2 = ((const float4*)(sim + 2 * P_PIX))[p4];
        const float4 v3 = ((const float4*)(sim + 3 * P_PIX))[p4];
        const int tbv[4] = {tb4.x, tb4.y, tb4.z, tb4.w};
        const int kbv[4] = {kb4.x, kb4.y, kb4.z, kb4.w};
        const v2f a01[4] = {{v0.x, v1.x}, {v0.y, v1.y}, {v0.z, v1.z}, {v0.w, v1.w}};
        const v2f a23[4] = {{v2.x, v3.x}, {v2.y, v3.y}, {v2.z, v3.z}, {v2.w, v3.w}};
        const int h = it >> 1;
        #pragma unroll
        for (int j = 0; j < 4; ++j) {
            const int kb = kbv[j], tb = tbv[j];
            kp[h] += 1ull << (4 * kb);
            tp[h] += 1ull << (4 * tb);
            v2f* p01 = (v2f*)&row01[kb * 2];
            v2f* p23 = (v2f*)&row23[kb * 2];
            *p01 = *p01 + a01[j];     // ds_read_b64 + v_pk_add + ds_write_b64
            *p23 = *p23 + a23[j];     // same-wave DS ops are pipe-ordered
        }
    }

    // counts: 4-bit -> 16-bit expansion (merge halves at 8-bit stage)
    const unsigned long long M4 = 0x0F0F0F0F0F0F0F0Full;
    const unsigned long long M8 = 0x00FF00FF00FF00FFull;
    unsigned int kc[8], tc[8];
    {
        unsigned long long e = (kp[0] & M4) + (kp[1] & M4);
        unsigned long long o = ((kp[0] >> 4) & M4) + ((kp[1] >> 4) & M4);
        unsigned long long e0 = e & M8, e1 = (e >> 8) & M8;
        unsigned long long o0 = o & M8, o1 = (o >> 8) & M8;
        kc[0] = (unsigned int)e0; kc[1] = (unsigned int)(e0 >> 32);
        kc[2] = (unsigned int)e1; kc[3] = (unsigned int)(e1 >> 32);
        kc[4] = (unsigned int)o0; kc[5] = (unsigned int)(o0 >> 32);
        kc[6] = (unsigned int)o1; kc[7] = (unsigned int)(o1 >> 32);
    }
    {
        unsigned long long e = (tp[0] & M4) + (tp[1] & M4);
        unsigned long long o = ((tp[0] >> 4) & M4) + ((tp[1] >> 4) & M4);
        unsigned long long e0 = e & M8, e1 = (e >> 8) & M8;
        unsigned long long o0 = o & M8, o1 = (o >> 8) & M8;
        tc[0] = (unsigned int)e0; tc[1] = (unsigned int)(e0 >> 32);
        tc[2] = (unsigned int)e1; tc[3] = (unsigned int)(e1 >> 32);
        tc[4] = (unsigned int)o0; tc[5] = (unsigned int)(o0 >> 32);
        tc[6] = (unsigned int)o1; tc[7] = (unsigned int)(o1 >> 32);
    }
    #pragma unroll
    for (int k = 0; k < 8; ++k) { kc[k] = wave_sum_u(kc[k]); tc[k] = wave_sum_u(tc[k]); }

    __shared__ unsigned int wk[2][8], wt[2][8];
    __shared__ float colred[64][2];
    if (lane == 63) {
        #pragma unroll
        for (int k = 0; k < 8; ++k) { wk[w][k] = kc[k]; wt[w][k] = tc[k]; }
    }
    __syncthreads();

    // ksum column sums: 64 cols x 128 rows; thread tid<128: col=tid&63,
    // half q=tid>>6 sums rows q*64..q*64+63
    {
        const int col = tid & 63;
        const int q = tid >> 6;
        const int bin = col >> 2, ch = col & 3;
        const int region = ch >> 1, sub = ch & 1;
        float sum = 0.0f;
        #pragma unroll 16
        for (int r = 0; r < 64; ++r)
            sum += acc[region][q * 64 + r][bin * 2 + sub];
        colred[col][q] = sum;
    }
    __syncthreads();

    float* part = ws + WS_STATS_OFF + (size_t)(s * NB1 + b) * SP_F;
    if (tid < 64) {
        const int bin = tid >> 2, ch = tid & 3;
        if (bin >= 1)
            part[15 + (bin - 1) * 4 + ch] = colred[tid][0] + colred[tid][1];
    } else if (tid >= 64 && tid < 94) {
        const int k = tid - 64;
        const int bin = (k < 15) ? (k + 1) : (k - 14);
        const unsigned int (*src)[8] = (k < 15) ? wk : wt;
        const int u = (bin & 1) * 2 + ((bin >> 1) & 1);
        const int f = bin >> 2;
        const int idx = u * 2 + (f >> 1);
        const int sh = (f & 1) * 16;
        const unsigned int sum = src[0][idx] + src[1][idx];
        part[(k < 15) ? k : (75 + k - 15)] = (float)((sum >> sh) & 0xFFFFu);
    }
}

// ---------------- K2: weighted loss (R11 linearity; __logf) ----------------

__global__ __launch_bounds__(256) void agg_loss_kernel(
        const float* __restrict__ preds,
        const int* __restrict__ targets,
        float* __restrict__ ws) {
    const int s = blockIdx.y;
    const int b = blockIdx.x;
    const int tid = threadIdx.x;
    const int lane = tid & 63;
    const int w = tid >> 6;

    __shared__ float tmp[90];
    __shared__ __align__(16) float4 G4[16];   // G4[0] = 0 (background dummy)
    __shared__ float w16[16];                 // w[t] = valid ? 1/t_cnt : 0
    __shared__ float ip[4];

    if (tid < 90) {
        const float* base = ws + WS_STATS_OFF + (size_t)s * NB1 * SP_F + tid;
        float v = 0.0f;
        #pragma unroll 8
        for (int pb = 0; pb < NB1; ++pb) v += base[pb * SP_F];
        tmp[tid] = v;
    }
    __syncthreads();
    if (tid < 60) ((float*)G4)[4 + tid] = tmp[15 + tid] / fmaxf(tmp[tid >> 2], 1.0f);
    if (tid >= 64 && tid < 68) ((float*)G4)[tid - 64] = 0.0f;
    if (tid < 16) {
        if (tid == 15) {
            w16[0] = 0.0f;
        } else {
            const float kcv = tmp[tid];
            const float tcv = tmp[75 + tid];
            w16[tid + 1] = (kcv > 0.0f && tcv > 0.0f) ? 1.0f / tcv : 0.0f;
        }
    }
    if (w == 0) {
        const bool vld = (tid < 15) && (tmp[tid] > 0.0f) && (tmp[75 + tid] > 0.0f);
        const unsigned long long m = __ballot(vld);
        if (b == 0 && tid == 0) {
            const float nv = (float)__popcll(m);
            ws[WS_SC_OFF + s] = (nv > 0.0f) ? 1.0f / nv : 0.0f;
        }
    }
    __syncthreads();

    const float* sim  = preds + (size_t)s * 6 * P_PIX + 2 * (size_t)P_PIX;
    const int*   text = targets + (size_t)s * 2 * P_PIX;

    float racc = 0.0f;
    #pragma unroll
    for (int it = 0; it < 2; ++it) {
        const int p4 = b * 512 + it * 256 + tid;
        const int4   tb4 = ((const int4*)text)[p4];
        const float4 v0 = ((const float4*)(sim))[p4];
        const float4 v1 = ((const float4*)(sim + P_PIX))[p4];
        const float4 v2 = ((const float4*)(sim + 2 * P_PIX))[p4];
        const float4 v3 = ((const float4*)(sim + 3 * P_PIX))[p4];
        const int tbv[4] = {tb4.x, tb4.y, tb4.z, tb4.w};
        const float a[4][4] = {{v0.x, v1.x, v2.x, v3.x}, {v0.y, v1.y, v2.y, v3.y},
                               {v0.z, v1.z, v2.z, v3.z}, {v0.w, v1.w, v2.w, v3.w}};
        #pragma unroll
        for (int j = 0; j < 4; ++j) {
            const int tb = tbv[j];
            const float4 g = G4[tb];
            const float wv = w16[tb];
            const float d0 = a[j][0] - g.x;
            const float d1 = a[j][1] - g.y;
            const float d2 = a[j][2] - g.z;
            const float d3 = a[j][3] - g.w;
            const float dd = sqrtf(d0 * d0 + d1 * d1 + d2 * d2 + d3 * d3) - 0.5f;
            const float r = fmaxf(dd, 0.0f);
            const float lp = __logf(fmaf(r, r, 1.0f));   // ln(1+r^2), v_log_f32
            racc = fmaf(lp, wv, racc);
        }
    }

    racc = wave_sum_f(racc);
    if (lane == 63) ip[w] = racc;
    __syncthreads();
    if (tid == 0)
        ws[WS_LP_OFF + (size_t)s * NB2 + b] = (ip[0] + ip[1]) + (ip[2] + ip[3]);
}

// ---------------- K3: per-sample sum of 32 partials x scale ----------------

__global__ __launch_bounds__(64) void agg_final_kernel(
        const float* __restrict__ ws, float* __restrict__ out) {
    const int s = blockIdx.x;
    const int tid = threadIdx.x;
    float v = (tid < NB2) ? ws[WS_LP_OFF + (size_t)s * NB2 + tid] : 0.0f;
    #pragma unroll
    for (int off = 32; off >= 1; off >>= 1) v += __shfl_down(v, off);
    if (tid == 0) out[s] = v * ws[WS_SC_OFF + s];
}

extern "C" void kernel_launch(void* const* d_in, const int* in_sizes, int n_in,
                              void* d_out, int out_size, void* d_ws, size_t ws_size,
                              hipStream_t stream) {
    const float* preds = (const float*)d_in[0];
    const int* targets = (const int*)d_in[1];
    float* out = (float*)d_out;
    float* ws = (float*)d_ws;

    agg_stats_kernel<<<dim3(NB1, NS), 128, 0, stream>>>(preds, targets, ws);
    agg_loss_kernel<<<dim3(NB2, NS), 256, 0, stream>>>(preds, targets, ws);
    agg_final_kernel<<<NS, 64, 0, stream>>>(ws, out);
}